// Round 8
// baseline (394.136 us; speedup 1.0000x reference)
//
#include <hip/hip_runtime.h>

#define B_ 32
#define C_ 256
#define N_ 1024
#define D_ 64

typedef __attribute__((ext_vector_type(16))) float f16v;

// key = (monotone(v) << 10) | (1023 - m): larger key <=> larger v, tie -> smaller m.
__device__ __forceinline__ unsigned long long pack_key(float v, int m) {
    const unsigned int bits = __float_as_uint(v);
    const unsigned int mono = (bits & 0x80000000u) ? ~bits : (bits | 0x80000000u);
    return ((unsigned long long)mono << 10) | (unsigned long long)(1023 - m);
}

// ---------------------------------------------------------------------------
// Kernel 0: transpose W_all = [wq(64); wk(64); wv(256)] into wt[c][384].
// ---------------------------------------------------------------------------
__global__ __launch_bounds__(384) void wt_kernel(
    const float* __restrict__ wq, const float* __restrict__ wk,
    const float* __restrict__ wv, float* __restrict__ wt)
{
    const int c = blockIdx.x;          // 0..255
    const int r = threadIdx.x;         // 0..383
    float v;
    if      (r < 64)  v = wq[(size_t)r * C_ + c];
    else if (r < 128) v = wk[(size_t)(r - 64) * C_ + c];
    else              v = wv[(size_t)(r - 128) * C_ + c];
    wt[(size_t)c * 384 + r] = v;
}

// ---------------------------------------------------------------------------
// Kernel 1: all projections, LDS-free, W-stationary streaming.
// Wave owns 8 output rows (uniform -> s_load W); lane owns 4 consecutive n.
// Ascending-c fmaf chain per (r,n) -> bit-exact np.einsum emulation.
// ---------------------------------------------------------------------------
__global__ __launch_bounds__(256) void proj_kernel(
    const float* __restrict__ x, const float* __restrict__ wt,
    const float* __restrict__ bq, const float* __restrict__ bk,
    const float* __restrict__ bv,
    float* __restrict__ qk, float* __restrict__ vt)
{
    const int rg = blockIdx.x;         // 0..11
    const int nt = blockIdx.y;         // 0..3
    const int b  = blockIdx.z;
    const int r0 = rg * 32;
    const int n0 = nt * 256;
    const int lane = threadIdx.x & 63;
    const int wu = __builtin_amdgcn_readfirstlane(threadIdx.x >> 6);
    const int rw = r0 + wu * 8;        // this wave's first row (uniform)

    float acc[8][4];
    #pragma unroll
    for (int i = 0; i < 8; ++i)
        #pragma unroll
        for (int j = 0; j < 4; ++j) acc[i][j] = 0.f;

    const float* xp = x + (size_t)b * C_ * N_ + n0 + lane * 4;
    const float* wp = wt + rw;

    #pragma unroll 8
    for (int c = 0; c < C_; ++c) {
        const float4 xv = *(const float4*)(xp + (size_t)c * N_);
        const float* wr = wp + (size_t)c * 384;
        const float4 w0 = *(const float4*)(wr);        // uniform -> s_load
        const float4 w1 = *(const float4*)(wr + 4);    // uniform -> s_load
        const float wv8[8] = { w0.x, w0.y, w0.z, w0.w, w1.x, w1.y, w1.z, w1.w };
        #pragma unroll
        for (int i = 0; i < 8; ++i) {
            acc[i][0] = fmaf(wv8[i], xv.x, acc[i][0]);
            acc[i][1] = fmaf(wv8[i], xv.y, acc[i][1]);
            acc[i][2] = fmaf(wv8[i], xv.z, acc[i][2]);
            acc[i][3] = fmaf(wv8[i], xv.w, acc[i][3]);
        }
    }

    if (r0 < 128) {
        #pragma unroll
        for (int i = 0; i < 8; ++i) {
            const int R = rw + i;
            const float bb = (R < 64) ? bq[R] : bk[R - 64];
            float4 o; o.x = acc[i][0]+bb; o.y = acc[i][1]+bb; o.z = acc[i][2]+bb; o.w = acc[i][3]+bb;
            *(float4*)&qk[((size_t)b * 128 + R) * N_ + n0 + lane * 4] = o;
        }
    } else {
        const int e0 = rw - 128;
        float be[8];
        #pragma unroll
        for (int i = 0; i < 8; ++i) be[i] = bv[e0 + i];
        #pragma unroll
        for (int j = 0; j < 4; ++j) {
            const int n = n0 + lane * 4 + j;
            float* dst = &vt[((size_t)b * N_ + n) * C_ + e0];
            float4 o0; o0.x = acc[0][j]+be[0]; o0.y = acc[1][j]+be[1]; o0.z = acc[2][j]+be[2]; o0.w = acc[3][j]+be[3];
            float4 o1; o1.x = acc[4][j]+be[4]; o1.y = acc[5][j]+be[5]; o1.z = acc[6][j]+be[6]; o1.w = acc[7][j]+be[7];
            *(float4*)dst       = o0;
            *(float4*)(dst + 4) = o1;
        }
    }
}

// ---------------------------------------------------------------------------
// Kernel 2: fp32 sim (bit-exact ascending-d fmaf chain; /8 exact, applied
// inside exp only) + threshold-filtered exact top-8 + softmax + V gather +
// residual.  Block = 32 rows x 8 waves (512 thr); wave w owns m-slice
// [128w, 128w+128), 2 m/lane.  q is wave-uniform -> s_load_dwordx16.
// cand: 32 rows x stride 134 u64 (cap 16/slice, exact fallback when >16);
// row reused as the 256-float output row after stage B.
// ---------------------------------------------------------------------------
__global__ __launch_bounds__(512) void attn_kernel(
    const float* __restrict__ x,
    const float* __restrict__ qk,
    const float* __restrict__ vt,
    const float* __restrict__ scale,
    float* __restrict__ out)
{
    const int b  = blockIdx.y;
    const int n0 = blockIdx.x * 32;
    const int t  = threadIdx.x;
    const int lane = t & 63;
    const int w  = t >> 6;

    __shared__ unsigned long long cand[32][134];   // 34304 B (rows 16B-aligned)
    __shared__ int ccnt[32][8];                    //  1024 B

    const int m_base = w * 128 + lane * 2;

    float a0[32], a1[32];
    #pragma unroll
    for (int r = 0; r < 32; ++r) { a0[r] = 0.f; a1[r] = 0.f; }

    const float* kb = qk + ((size_t)b * 128 + 64) * N_ + m_base;
    const f16v*  qv = (const f16v*)(qk + (size_t)b * 128 * N_) + (n0 >> 4);

    #pragma unroll 1
    for (int d = 0; d < D_; d += 2) {
        // wave-uniform q: 2 d x 32 rows -> 4x s_load_dwordx16
        const f16v qa_lo = qv[(size_t)(d+0) * 64];
        const f16v qa_hi = qv[(size_t)(d+0) * 64 + 1];
        const f16v qb_lo = qv[(size_t)(d+1) * 64];
        const f16v qb_hi = qv[(size_t)(d+1) * 64 + 1];
        const float2 k0 = *(const float2*)&kb[(size_t)(d+0) * N_];
        const float2 k1 = *(const float2*)&kb[(size_t)(d+1) * N_];

        #pragma unroll
        for (int r = 0; r < 16; ++r) {
            a0[r] = fmaf(qa_lo[r], k0.x, a0[r]); a0[r] = fmaf(qb_lo[r], k1.x, a0[r]);
            a1[r] = fmaf(qa_lo[r], k0.y, a1[r]); a1[r] = fmaf(qb_lo[r], k1.y, a1[r]);
        }
        #pragma unroll
        for (int r = 0; r < 16; ++r) {
            a0[r+16] = fmaf(qa_hi[r], k0.x, a0[r+16]); a0[r+16] = fmaf(qb_hi[r], k1.x, a0[r+16]);
            a1[r+16] = fmaf(qa_hi[r], k0.y, a1[r+16]); a1[r+16] = fmaf(qb_hi[r], k1.y, a1[r+16]);
        }
    }

    // ---- stage A: per-slice threshold filter + compaction (exact superset) ----
    const unsigned long long lt = (1ull << lane) - 1ull;
    #pragma unroll
    for (int r = 0; r < 32; ++r) {
        const int nrow = n0 + r;
        float t0 = a0[r], t1 = a1[r];
        const int dj = nrow - m_base;
        if      (dj == 0) t0 = -1.0e9f;
        else if (dj == 1) t1 = -1.0e9f;

        float lm = fmaxf(t0, t1);
        lm = fmaxf(lm, __shfl_xor(lm, 1));
        lm = fmaxf(lm, __shfl_xor(lm, 2));
        lm = fmaxf(lm, __shfl_xor(lm, 4));      // max over group of 8 lanes (16 m)
        float Th = lm;
        Th = fminf(Th, __shfl_xor(Th, 8));
        Th = fminf(Th, __shfl_xor(Th, 16));
        Th = fminf(Th, __shfl_xor(Th, 32));     // min of 8 group maxes <= slice V8

        int cnt = 0;
        {
            const bool p = (t0 >= Th);
            const unsigned long long msk = __ballot(p);
            const int pos = cnt + (int)__popcll(msk & lt);
            if (p && pos < 16) cand[r][w * 16 + pos] = pack_key(t0, m_base + 0);
            cnt += (int)__popcll(msk);
        }
        {
            const bool p = (t1 >= Th);
            const unsigned long long msk = __ballot(p);
            const int pos = cnt + (int)__popcll(msk & lt);
            if (p && pos < 16) cand[r][w * 16 + pos] = pack_key(t1, m_base + 1);
            cnt += (int)__popcll(msk);
        }

        if (cnt > 16) {   // exact fallback: slice top-8 via 8 extraction rounds
            unsigned long long K0 = pack_key(t0, m_base + 0);
            unsigned long long K1 = pack_key(t1, m_base + 1);
            #pragma unroll 1
            for (int round = 0; round < 8; ++round) {
                unsigned long long kl = K0 > K1 ? K0 : K1;
                #pragma unroll
                for (int off = 32; off >= 1; off >>= 1) {
                    const unsigned long long ks = __shfl_xor(kl, off);
                    if (ks > kl) kl = ks;
                }
                if (lane == 0) cand[r][w * 16 + round] = kl;
                if      (K0 == kl) K0 = 0ull;
                else if (K1 == kl) K1 = 0ull;
            }
            cnt = 8;
        }
        if (lane == 0) ccnt[r][w] = cnt;
    }
    __syncthreads();

    // ---- stage B: per-row exact top-8 over 8 slices + softmax + V gather ----
    const float* vtb = vt + (size_t)b * N_ * C_;
    #pragma unroll 1
    for (int rr = 0; rr < 4; ++rr) {
        const int r = w * 4 + rr;
        const int seg = lane >> 3;      // 0..7
        const int i0  = lane & 7;       // 0..7
        const int cn  = ccnt[r][seg];
        unsigned long long k0 = (i0     < cn) ? cand[r][seg * 16 + i0    ] : 0ull;
        unsigned long long k1 = (i0 + 8 < cn) ? cand[r][seg * 16 + i0 + 8] : 0ull;

        float ev[8]; unsigned int mi[8];
        float S = 0.f, vmax = 0.f;
        #pragma unroll
        for (int round = 0; round < 8; ++round) {
            unsigned long long km = k0 > k1 ? k0 : k1;
            #pragma unroll
            for (int off = 32; off >= 1; off >>= 1) {
                const unsigned long long ks = __shfl_xor(km, off);
                if (ks > km) km = ks;
            }
            const unsigned int mono = (unsigned int)(km >> 10);
            mi[round] = 1023u - ((unsigned int)km & 1023u);
            const unsigned int bits = (mono & 0x80000000u) ? (mono & 0x7FFFFFFFu) : ~mono;
            const float vraw = __uint_as_float(bits);
            if (round == 0) vmax = vraw;
            const float e = __expf((vraw - vmax) * 0.125f);
            S += e;
            ev[round] = e;
            if (k0 == km) k0 = 0ull;
            if (k1 == km) k1 = 0ull;
        }

        // batched gathers: 8 independent L2 loads in flight
        float4 o = make_float4(0.f, 0.f, 0.f, 0.f);
        #pragma unroll
        for (int round = 0; round < 8; ++round) {
            const float4 vv = *(const float4*)&vtb[(size_t)mi[round] * C_ + lane * 4];
            o.x += ev[round] * vv.x; o.y += ev[round] * vv.y;
            o.z += ev[round] * vv.z; o.w += ev[round] * vv.w;
        }
        const float inv = 1.f / S;
        float* orow = (float*)&cand[r][0];   // union: out row over cand row r
        *(float4*)&orow[lane * 4] = make_float4(o.x*inv, o.y*inv, o.z*inv, o.w*inv);
    }
    __syncthreads();

    // ---- residual + (b, c, n) write ----
    const float sc = scale[0];
    const float* xb = x + (size_t)b * C_ * N_;
    float* ob = out + (size_t)b * C_ * N_;
    const int nl = t & 31;
    const int cg = t >> 5;               // 0..15
    const float* orow = (const float*)&cand[nl][0];
    #pragma unroll
    for (int i = 0; i < 16; ++i) {
        const int cc = i * 16 + cg;
        const size_t gi = (size_t)cc * N_ + n0 + nl;
        ob[gi] = xb[gi] + sc * orow[cc];
    }
}

extern "C" void kernel_launch(void* const* d_in, const int* in_sizes, int n_in,
                              void* d_out, int out_size, void* d_ws, size_t ws_size,
                              hipStream_t stream) {
    const float* x     = (const float*)d_in[0];
    const float* wq    = (const float*)d_in[1];
    const float* bq    = (const float*)d_in[2];
    const float* wk    = (const float*)d_in[3];
    const float* bk    = (const float*)d_in[4];
    const float* wv    = (const float*)d_in[5];
    const float* bv    = (const float*)d_in[6];
    const float* scale = (const float*)d_in[7];
    float* out = (float*)d_out;

    float* qk = (float*)d_ws;                    // (b,128,n) fp32 = 16.8 MB
    float* vt = qk + (size_t)B_ * 128 * N_;      // (b,n,c)  fp32 = 33.6 MB
    float* wt = vt + (size_t)B_ * N_ * C_;       // (c,384)  fp32 =  0.4 MB

    wt_kernel<<<dim3(256), 384, 0, stream>>>(wq, wk, wv, wt);
    proj_kernel<<<dim3(12, 4, B_), 256, 0, stream>>>(x, wt, bq, bk, bv, qk, vt);
    attn_kernel<<<dim3(N_ / 32, B_), 512, 0, stream>>>(x, qk, vt, scale, out);
}

// Round 9
// 391.876 us; speedup vs baseline: 1.0058x; 1.0058x over previous
//
#include <hip/hip_runtime.h>

#define B_ 32
#define C_ 256
#define N_ 1024
#define D_ 64

typedef __attribute__((ext_vector_type(16))) float f16v;

// key = (monotone(v) << 10) | (1023 - m): larger key <=> larger v, tie -> smaller m.
__device__ __forceinline__ unsigned long long pack_key(float v, int m) {
    const unsigned int bits = __float_as_uint(v);
    const unsigned int mono = (bits & 0x80000000u) ? ~bits : (bits | 0x80000000u);
    return ((unsigned long long)mono << 10) | (unsigned long long)(1023 - m);
}

// ---------------------------------------------------------------------------
// Kernel 0: transpose W_all = [wq(64); wk(64); wv(256)] into wt[c][384].
// ---------------------------------------------------------------------------
__global__ __launch_bounds__(384) void wt_kernel(
    const float* __restrict__ wq, const float* __restrict__ wk,
    const float* __restrict__ wv, float* __restrict__ wt)
{
    const int c = blockIdx.x;          // 0..255
    const int r = threadIdx.x;         // 0..383
    float v;
    if      (r < 64)  v = wq[(size_t)r * C_ + c];
    else if (r < 128) v = wk[(size_t)(r - 64) * C_ + c];
    else              v = wv[(size_t)(r - 128) * C_ + c];
    wt[(size_t)c * 384 + r] = v;
}

// ---------------------------------------------------------------------------
// Kernel 1: all projections, LDS-free, W-stationary streaming.
// Wave owns 8 output rows (uniform -> s_load W); lane owns 4 consecutive n.
// Ascending-c fmaf chain per (r,n) -> bit-exact np.einsum emulation.
// ---------------------------------------------------------------------------
__global__ __launch_bounds__(256) void proj_kernel(
    const float* __restrict__ x, const float* __restrict__ wt,
    const float* __restrict__ bq, const float* __restrict__ bk,
    const float* __restrict__ bv,
    float* __restrict__ qk, float* __restrict__ vt)
{
    const int rg = blockIdx.x;         // 0..11
    const int nt = blockIdx.y;         // 0..3
    const int b  = blockIdx.z;
    const int r0 = rg * 32;
    const int n0 = nt * 256;
    const int lane = threadIdx.x & 63;
    const int wu = __builtin_amdgcn_readfirstlane(threadIdx.x >> 6);
    const int rw = r0 + wu * 8;        // this wave's first row (uniform)

    float acc[8][4];
    #pragma unroll
    for (int i = 0; i < 8; ++i)
        #pragma unroll
        for (int j = 0; j < 4; ++j) acc[i][j] = 0.f;

    const float* xp = x + (size_t)b * C_ * N_ + n0 + lane * 4;
    const float* wp = wt + rw;

    #pragma unroll 8
    for (int c = 0; c < C_; ++c) {
        const float4 xv = *(const float4*)(xp + (size_t)c * N_);
        const float* wr = wp + (size_t)c * 384;
        const float4 w0 = *(const float4*)(wr);        // uniform -> s_load
        const float4 w1 = *(const float4*)(wr + 4);    // uniform -> s_load
        const float wv8[8] = { w0.x, w0.y, w0.z, w0.w, w1.x, w1.y, w1.z, w1.w };
        #pragma unroll
        for (int i = 0; i < 8; ++i) {
            acc[i][0] = fmaf(wv8[i], xv.x, acc[i][0]);
            acc[i][1] = fmaf(wv8[i], xv.y, acc[i][1]);
            acc[i][2] = fmaf(wv8[i], xv.z, acc[i][2]);
            acc[i][3] = fmaf(wv8[i], xv.w, acc[i][3]);
        }
    }

    if (r0 < 128) {
        #pragma unroll
        for (int i = 0; i < 8; ++i) {
            const int R = rw + i;
            const float bb = (R < 64) ? bq[R] : bk[R - 64];
            float4 o; o.x = acc[i][0]+bb; o.y = acc[i][1]+bb; o.z = acc[i][2]+bb; o.w = acc[i][3]+bb;
            *(float4*)&qk[((size_t)b * 128 + R) * N_ + n0 + lane * 4] = o;
        }
    } else {
        const int e0 = rw - 128;
        float be[8];
        #pragma unroll
        for (int i = 0; i < 8; ++i) be[i] = bv[e0 + i];
        #pragma unroll
        for (int j = 0; j < 4; ++j) {
            const int n = n0 + lane * 4 + j;
            float* dst = &vt[((size_t)b * N_ + n) * C_ + e0];
            float4 o0; o0.x = acc[0][j]+be[0]; o0.y = acc[1][j]+be[1]; o0.z = acc[2][j]+be[2]; o0.w = acc[3][j]+be[3];
            float4 o1; o1.x = acc[4][j]+be[4]; o1.y = acc[5][j]+be[5]; o1.z = acc[6][j]+be[6]; o1.w = acc[7][j]+be[7];
            *(float4*)dst       = o0;
            *(float4*)(dst + 4) = o1;
        }
    }
}

// ---------------------------------------------------------------------------
// Kernel 2: fp32 sim (bit-exact ascending-d fmaf chain; /8 exact, applied
// inside exp only) + threshold-filtered exact top-8 + softmax + V gather +
// residual.  Block = 32 rows x 8 waves (512 thr); wave w owns m-slice
// [128w, 128w+128), 2 m/lane.  q is wave-uniform -> s_load_dwordx16.
// __launch_bounds__(512, 4): VGPR cap 128 so the 64 fp32 accumulators stay
// in registers (r8 spilled at the default 8-waves/EU 64-VGPR cap).
// cand: 32 rows x stride 134 u64 (cap 16/slice, exact fallback when >16);
// row reused as the 256-float output row after stage B.
// ---------------------------------------------------------------------------
__global__ __launch_bounds__(512, 4) void attn_kernel(
    const float* __restrict__ x,
    const float* __restrict__ qk,
    const float* __restrict__ vt,
    const float* __restrict__ scale,
    float* __restrict__ out)
{
    const int b  = blockIdx.y;
    const int n0 = blockIdx.x * 32;
    const int t  = threadIdx.x;
    const int lane = t & 63;
    const int w  = t >> 6;

    __shared__ unsigned long long cand[32][134];   // 34304 B (rows 16B-aligned)
    __shared__ int ccnt[32][8];                    //  1024 B

    const int m_base = w * 128 + lane * 2;

    float a0[32], a1[32];
    #pragma unroll
    for (int r = 0; r < 32; ++r) { a0[r] = 0.f; a1[r] = 0.f; }

    const float* kb = qk + ((size_t)b * 128 + 64) * N_ + m_base;
    const f16v*  qv = (const f16v*)(qk + (size_t)b * 128 * N_) + (n0 >> 4);

    #pragma unroll 2
    for (int d = 0; d < D_; d += 2) {
        // wave-uniform q: 2 d x 32 rows -> 4x s_load_dwordx16
        const f16v qa_lo = qv[(size_t)(d+0) * 64];
        const f16v qa_hi = qv[(size_t)(d+0) * 64 + 1];
        const f16v qb_lo = qv[(size_t)(d+1) * 64];
        const f16v qb_hi = qv[(size_t)(d+1) * 64 + 1];
        const float2 k0 = *(const float2*)&kb[(size_t)(d+0) * N_];
        const float2 k1 = *(const float2*)&kb[(size_t)(d+1) * N_];

        #pragma unroll
        for (int r = 0; r < 16; ++r) {
            a0[r] = fmaf(qa_lo[r], k0.x, a0[r]); a0[r] = fmaf(qb_lo[r], k1.x, a0[r]);
            a1[r] = fmaf(qa_lo[r], k0.y, a1[r]); a1[r] = fmaf(qb_lo[r], k1.y, a1[r]);
        }
        #pragma unroll
        for (int r = 0; r < 16; ++r) {
            a0[r+16] = fmaf(qa_hi[r], k0.x, a0[r+16]); a0[r+16] = fmaf(qb_hi[r], k1.x, a0[r+16]);
            a1[r+16] = fmaf(qa_hi[r], k0.y, a1[r+16]); a1[r+16] = fmaf(qb_hi[r], k1.y, a1[r+16]);
        }
    }

    // ---- stage A: per-slice threshold filter + compaction (exact superset) ----
    const unsigned long long lt = (1ull << lane) - 1ull;
    #pragma unroll
    for (int r = 0; r < 32; ++r) {
        const int nrow = n0 + r;
        float t0 = a0[r], t1 = a1[r];
        const int dj = nrow - m_base;
        if      (dj == 0) t0 = -1.0e9f;
        else if (dj == 1) t1 = -1.0e9f;

        float lm = fmaxf(t0, t1);
        lm = fmaxf(lm, __shfl_xor(lm, 1));
        lm = fmaxf(lm, __shfl_xor(lm, 2));
        lm = fmaxf(lm, __shfl_xor(lm, 4));      // max over group of 8 lanes (16 m)
        float Th = lm;
        Th = fminf(Th, __shfl_xor(Th, 8));
        Th = fminf(Th, __shfl_xor(Th, 16));
        Th = fminf(Th, __shfl_xor(Th, 32));     // min of 8 group maxes <= slice V8

        int cnt = 0;
        {
            const bool p = (t0 >= Th);
            const unsigned long long msk = __ballot(p);
            const int pos = cnt + (int)__popcll(msk & lt);
            if (p && pos < 16) cand[r][w * 16 + pos] = pack_key(t0, m_base + 0);
            cnt += (int)__popcll(msk);
        }
        {
            const bool p = (t1 >= Th);
            const unsigned long long msk = __ballot(p);
            const int pos = cnt + (int)__popcll(msk & lt);
            if (p && pos < 16) cand[r][w * 16 + pos] = pack_key(t1, m_base + 1);
            cnt += (int)__popcll(msk);
        }

        if (cnt > 16) {   // exact fallback: slice top-8 via 8 extraction rounds
            unsigned long long K0 = pack_key(t0, m_base + 0);
            unsigned long long K1 = pack_key(t1, m_base + 1);
            #pragma unroll 1
            for (int round = 0; round < 8; ++round) {
                unsigned long long kl = K0 > K1 ? K0 : K1;
                #pragma unroll
                for (int off = 32; off >= 1; off >>= 1) {
                    const unsigned long long ks = __shfl_xor(kl, off);
                    if (ks > kl) kl = ks;
                }
                if (lane == 0) cand[r][w * 16 + round] = kl;
                if      (K0 == kl) K0 = 0ull;
                else if (K1 == kl) K1 = 0ull;
            }
            cnt = 8;
        }
        if (lane == 0) ccnt[r][w] = cnt;
    }
    __syncthreads();

    // ---- stage B: per-row exact top-8 over 8 slices + softmax + V gather ----
    const float* vtb = vt + (size_t)b * N_ * C_;
    #pragma unroll 1
    for (int rr = 0; rr < 4; ++rr) {
        const int r = w * 4 + rr;
        const int seg = lane >> 3;      // 0..7
        const int i0  = lane & 7;       // 0..7
        const int cn  = ccnt[r][seg];
        unsigned long long k0 = (i0     < cn) ? cand[r][seg * 16 + i0    ] : 0ull;
        unsigned long long k1 = (i0 + 8 < cn) ? cand[r][seg * 16 + i0 + 8] : 0ull;

        float ev[8]; unsigned int mi[8];
        float S = 0.f, vmax = 0.f;
        #pragma unroll
        for (int round = 0; round < 8; ++round) {
            unsigned long long km = k0 > k1 ? k0 : k1;
            #pragma unroll
            for (int off = 32; off >= 1; off >>= 1) {
                const unsigned long long ks = __shfl_xor(km, off);
                if (ks > km) km = ks;
            }
            const unsigned int mono = (unsigned int)(km >> 10);
            mi[round] = 1023u - ((unsigned int)km & 1023u);
            const unsigned int bits = (mono & 0x80000000u) ? (mono & 0x7FFFFFFFu) : ~mono;
            const float vraw = __uint_as_float(bits);
            if (round == 0) vmax = vraw;
            const float e = __expf((vraw - vmax) * 0.125f);
            S += e;
            ev[round] = e;
            if (k0 == km) k0 = 0ull;
            if (k1 == km) k1 = 0ull;
        }

        // batched gathers: 8 independent L2 loads in flight
        float4 o = make_float4(0.f, 0.f, 0.f, 0.f);
        #pragma unroll
        for (int round = 0; round < 8; ++round) {
            const float4 vv = *(const float4*)&vtb[(size_t)mi[round] * C_ + lane * 4];
            o.x += ev[round] * vv.x; o.y += ev[round] * vv.y;
            o.z += ev[round] * vv.z; o.w += ev[round] * vv.w;
        }
        const float inv = 1.f / S;
        float* orow = (float*)&cand[r][0];   // union: out row over cand row r
        *(float4*)&orow[lane * 4] = make_float4(o.x*inv, o.y*inv, o.z*inv, o.w*inv);
    }
    __syncthreads();

    // ---- residual + (b, c, n) write ----
    const float sc = scale[0];
    const float* xb = x + (size_t)b * C_ * N_;
    float* ob = out + (size_t)b * C_ * N_;
    const int nl = t & 31;
    const int cg = t >> 5;               // 0..15
    const float* orow = (const float*)&cand[nl][0];
    #pragma unroll
    for (int i = 0; i < 16; ++i) {
        const int cc = i * 16 + cg;
        const size_t gi = (size_t)cc * N_ + n0 + nl;
        ob[gi] = xb[gi] + sc * orow[cc];
    }
}

extern "C" void kernel_launch(void* const* d_in, const int* in_sizes, int n_in,
                              void* d_out, int out_size, void* d_ws, size_t ws_size,
                              hipStream_t stream) {
    const float* x     = (const float*)d_in[0];
    const float* wq    = (const float*)d_in[1];
    const float* bq    = (const float*)d_in[2];
    const float* wk    = (const float*)d_in[3];
    const float* bk    = (const float*)d_in[4];
    const float* wv    = (const float*)d_in[5];
    const float* bv    = (const float*)d_in[6];
    const float* scale = (const float*)d_in[7];
    float* out = (float*)d_out;

    float* qk = (float*)d_ws;                    // (b,128,n) fp32 = 16.8 MB
    float* vt = qk + (size_t)B_ * 128 * N_;      // (b,n,c)  fp32 = 33.6 MB
    float* wt = vt + (size_t)B_ * N_ * C_;       // (c,384)  fp32 =  0.4 MB

    wt_kernel<<<dim3(256), 384, 0, stream>>>(wq, wk, wv, wt);
    proj_kernel<<<dim3(12, 4, B_), 256, 0, stream>>>(x, wt, bq, bk, bv, qk, vt);
    attn_kernel<<<dim3(N_ / 32, B_), 512, 0, stream>>>(x, qk, vt, scale, out);
}

// Round 10
// 230.810 us; speedup vs baseline: 1.7076x; 1.6978x over previous
//
#include <hip/hip_runtime.h>

#define B_ 32
#define C_ 256
#define N_ 1024
#define D_ 64

// key = (monotone(v) << 10) | (1023 - m): larger key <=> larger v, tie -> smaller m.
__device__ __forceinline__ unsigned long long pack_key(float v, int m) {
    const unsigned int bits = __float_as_uint(v);
    const unsigned int mono = (bits & 0x80000000u) ? ~bits : (bits | 0x80000000u);
    return ((unsigned long long)mono << 10) | (unsigned long long)(1023 - m);
}

// ---------------------------------------------------------------------------
// Kernel 0: transpose W_all = [wq(64); wk(64); wv(256)] into wt[c][384].
// ---------------------------------------------------------------------------
__global__ __launch_bounds__(384) void wt_kernel(
    const float* __restrict__ wq, const float* __restrict__ wk,
    const float* __restrict__ wv, float* __restrict__ wt)
{
    const int c = blockIdx.x;          // 0..255
    const int r = threadIdx.x;         // 0..383
    float v;
    if      (r < 64)  v = wq[(size_t)r * C_ + c];
    else if (r < 128) v = wk[(size_t)(r - 64) * C_ + c];
    else              v = wv[(size_t)(r - 128) * C_ + c];
    wt[(size_t)c * 384 + r] = v;
}

// ---------------------------------------------------------------------------
// Kernel 1: all projections, LDS-free, W-stationary streaming.
// Wave owns 8 output rows (uniform -> s_load W); lane owns 4 consecutive n.
// Ascending-c fmaf chain per (r,n) -> bit-exact np.einsum emulation.
// ---------------------------------------------------------------------------
__global__ __launch_bounds__(256) void proj_kernel(
    const float* __restrict__ x, const float* __restrict__ wt,
    const float* __restrict__ bq, const float* __restrict__ bk,
    const float* __restrict__ bv,
    float* __restrict__ qk, float* __restrict__ vt)
{
    const int rg = blockIdx.x;         // 0..11
    const int nt = blockIdx.y;         // 0..3
    const int b  = blockIdx.z;
    const int r0 = rg * 32;
    const int n0 = nt * 256;
    const int lane = threadIdx.x & 63;
    const int wu = __builtin_amdgcn_readfirstlane(threadIdx.x >> 6);
    const int rw = r0 + wu * 8;        // this wave's first row (uniform)

    float acc[8][4];
    #pragma unroll
    for (int i = 0; i < 8; ++i)
        #pragma unroll
        for (int j = 0; j < 4; ++j) acc[i][j] = 0.f;

    const float* xp = x + (size_t)b * C_ * N_ + n0 + lane * 4;
    const float* wp = wt + rw;

    #pragma unroll 8
    for (int c = 0; c < C_; ++c) {
        const float4 xv = *(const float4*)(xp + (size_t)c * N_);
        const float* wr = wp + (size_t)c * 384;
        const float4 w0 = *(const float4*)(wr);        // uniform -> s_load
        const float4 w1 = *(const float4*)(wr + 4);    // uniform -> s_load
        const float wv8[8] = { w0.x, w0.y, w0.z, w0.w, w1.x, w1.y, w1.z, w1.w };
        #pragma unroll
        for (int i = 0; i < 8; ++i) {
            acc[i][0] = fmaf(wv8[i], xv.x, acc[i][0]);
            acc[i][1] = fmaf(wv8[i], xv.y, acc[i][1]);
            acc[i][2] = fmaf(wv8[i], xv.z, acc[i][2]);
            acc[i][3] = fmaf(wv8[i], xv.w, acc[i][3]);
        }
    }

    if (r0 < 128) {
        #pragma unroll
        for (int i = 0; i < 8; ++i) {
            const int R = rw + i;
            const float bb = (R < 64) ? bq[R] : bk[R - 64];
            float4 o; o.x = acc[i][0]+bb; o.y = acc[i][1]+bb; o.z = acc[i][2]+bb; o.w = acc[i][3]+bb;
            *(float4*)&qk[((size_t)b * 128 + R) * N_ + n0 + lane * 4] = o;
        }
    } else {
        const int e0 = rw - 128;
        float be[8];
        #pragma unroll
        for (int i = 0; i < 8; ++i) be[i] = bv[e0 + i];
        #pragma unroll
        for (int j = 0; j < 4; ++j) {
            const int n = n0 + lane * 4 + j;
            float* dst = &vt[((size_t)b * N_ + n) * C_ + e0];
            float4 o0; o0.x = acc[0][j]+be[0]; o0.y = acc[1][j]+be[1]; o0.z = acc[2][j]+be[2]; o0.w = acc[3][j]+be[3];
            float4 o1; o1.x = acc[4][j]+be[4]; o1.y = acc[5][j]+be[5]; o1.z = acc[6][j]+be[6]; o1.w = acc[7][j]+be[7];
            *(float4*)dst       = o0;
            *(float4*)(dst + 4) = o1;
        }
    }
}

// ---------------------------------------------------------------------------
// Kernel 2: fp32 sim (bit-exact ascending-d fmaf chain; /8 exact, applied
// inside exp only) + threshold-filtered exact top-8 + softmax + V gather +
// residual.  Block = 16 rows x 8 waves (512 thr); wave w owns m-slice
// [128w, 128w+128), 2 m/lane.
// q is wave-uniform -> float4 loads that scalarize to s_load_dwordx4
// (ext_vector_type(16) loads do NOT scalarize -- r8/r9 lesson: they blow the
// VGPR budget and force accumulators into AGPR shuffles).
// Software pipeline at d-pair depth: prefetch next pair's K (VGPR) and
// q (SGPR, 32 scalars) before the current pair's 64-FMA block.
// ---------------------------------------------------------------------------
__global__ __launch_bounds__(512) void attn_kernel(
    const float* __restrict__ x,
    const float* __restrict__ qk,
    const float* __restrict__ vt,
    const float* __restrict__ scale,
    float* __restrict__ out)
{
    const int b  = blockIdx.y;
    const int n0 = blockIdx.x * 16;
    const int t  = threadIdx.x;
    const int lane = t & 63;
    const int w  = t >> 6;

    // cand row stride 266 u64 = 2128 B (16B-aligned rows); reused as the
    // 256-float output row after stage B.
    __shared__ unsigned long long cand[16][266];   // 34048 B
    __shared__ int   ccnt[16][8];                  //   512 B

    const int m_base = w * 128 + lane * 2;

    float a0[16], a1[16];
    #pragma unroll
    for (int r = 0; r < 16; ++r) { a0[r] = 0.f; a1[r] = 0.f; }

    const float* kb = qk + ((size_t)b * 128 + 64) * N_ + m_base;
    const float* qb = qk + (size_t)b * 128 * N_ + n0;   // uniform base

    // ---- prologue: load d-pair 0 ----
    float2 kc0 = *(const float2*)&kb[0 * N_];
    float2 kc1 = *(const float2*)&kb[1 * N_];
    float qc0[16], qc1[16];
    #pragma unroll
    for (int rq = 0; rq < 4; ++rq) {
        const float4 qa = *(const float4*)&qb[(size_t)0 * N_ + rq * 4];
        const float4 qv = *(const float4*)&qb[(size_t)1 * N_ + rq * 4];
        qc0[rq*4+0] = qa.x; qc0[rq*4+1] = qa.y; qc0[rq*4+2] = qa.z; qc0[rq*4+3] = qa.w;
        qc1[rq*4+0] = qv.x; qc1[rq*4+1] = qv.y; qc1[rq*4+2] = qv.z; qc1[rq*4+3] = qv.w;
    }

    #pragma unroll 1
    for (int d = 0; d < D_; d += 2) {
        float2 kn0, kn1;
        float qn0[16], qn1[16];
        if (d + 2 < D_) {
            kn0 = *(const float2*)&kb[(size_t)(d+2) * N_];
            kn1 = *(const float2*)&kb[(size_t)(d+3) * N_];
            #pragma unroll
            for (int rq = 0; rq < 4; ++rq) {
                const float4 qa = *(const float4*)&qb[(size_t)(d+2) * N_ + rq * 4];
                const float4 qv = *(const float4*)&qb[(size_t)(d+3) * N_ + rq * 4];
                qn0[rq*4+0] = qa.x; qn0[rq*4+1] = qa.y; qn0[rq*4+2] = qa.z; qn0[rq*4+3] = qa.w;
                qn1[rq*4+0] = qv.x; qn1[rq*4+1] = qv.y; qn1[rq*4+2] = qv.z; qn1[rq*4+3] = qv.w;
            }
        }

        #pragma unroll
        for (int r = 0; r < 16; ++r) {
            a0[r] = fmaf(qc0[r], kc0.x, a0[r]); a0[r] = fmaf(qc1[r], kc1.x, a0[r]);
            a1[r] = fmaf(qc0[r], kc0.y, a1[r]); a1[r] = fmaf(qc1[r], kc1.y, a1[r]);
        }

        if (d + 2 < D_) {
            kc0 = kn0; kc1 = kn1;
            #pragma unroll
            for (int i = 0; i < 16; ++i) { qc0[i] = qn0[i]; qc1[i] = qn1[i]; }
        }
    }

    // ---- stage A: per-slice threshold filter + compaction (exact superset) ----
    const unsigned long long lt = (1ull << lane) - 1ull;
    #pragma unroll
    for (int r = 0; r < 16; ++r) {
        const int nrow = n0 + r;
        float t0 = a0[r], t1 = a1[r];
        const int dj = nrow - m_base;
        if      (dj == 0) t0 = -1.0e9f;
        else if (dj == 1) t1 = -1.0e9f;

        float lm = fmaxf(t0, t1);
        lm = fmaxf(lm, __shfl_xor(lm, 1));
        lm = fmaxf(lm, __shfl_xor(lm, 2));
        lm = fmaxf(lm, __shfl_xor(lm, 4));      // max over group of 8 lanes (16 m)
        float Th = lm;
        Th = fminf(Th, __shfl_xor(Th, 8));
        Th = fminf(Th, __shfl_xor(Th, 16));
        Th = fminf(Th, __shfl_xor(Th, 32));     // min of 8 group maxes <= slice V8

        int cnt = 0;
        {
            const bool p = (t0 >= Th);
            const unsigned long long msk = __ballot(p);
            const int pos = cnt + (int)__popcll(msk & lt);
            if (p && pos < 32) cand[r][w * 33 + pos] = pack_key(t0, m_base + 0);
            cnt += (int)__popcll(msk);
        }
        {
            const bool p = (t1 >= Th);
            const unsigned long long msk = __ballot(p);
            const int pos = cnt + (int)__popcll(msk & lt);
            if (p && pos < 32) cand[r][w * 33 + pos] = pack_key(t1, m_base + 1);
            cnt += (int)__popcll(msk);
        }

        if (cnt > 32) {   // exact fallback: slice top-8 via 8 extraction rounds
            unsigned long long K0 = pack_key(t0, m_base + 0);
            unsigned long long K1 = pack_key(t1, m_base + 1);
            #pragma unroll 1
            for (int round = 0; round < 8; ++round) {
                unsigned long long kl = K0 > K1 ? K0 : K1;
                #pragma unroll
                for (int off = 32; off >= 1; off >>= 1) {
                    const unsigned long long ks = __shfl_xor(kl, off);
                    if (ks > kl) kl = ks;
                }
                if (lane == 0) cand[r][w * 33 + round] = kl;
                if      (K0 == kl) K0 = 0ull;
                else if (K1 == kl) K1 = 0ull;
            }
            cnt = 8;
        }
        if (lane == 0) ccnt[r][w] = cnt;
    }
    __syncthreads();

    // ---- stage B: per-row exact top-8 over 8 slices + softmax + V gather ----
    const float* vtb = vt + (size_t)b * N_ * C_;
    #pragma unroll 1
    for (int rr = 0; rr < 2; ++rr) {
        const int r = w * 2 + rr;
        const int seg = lane >> 3;      // 0..7
        const int i0  = lane & 7;       // 0..7
        const int cn  = ccnt[r][seg];
        unsigned long long k0 = (i0      < cn) ? cand[r][seg * 33 + i0     ] : 0ull;
        unsigned long long k1 = (i0 + 8  < cn) ? cand[r][seg * 33 + i0 + 8 ] : 0ull;
        unsigned long long k2 = (i0 + 16 < cn) ? cand[r][seg * 33 + i0 + 16] : 0ull;
        unsigned long long k3 = (i0 + 24 < cn) ? cand[r][seg * 33 + i0 + 24] : 0ull;

        float ev[8]; unsigned int mi[8];
        float S = 0.f, vmax = 0.f;
        #pragma unroll
        for (int round = 0; round < 8; ++round) {
            unsigned long long km = k0 > k1 ? k0 : k1;
            km = k2 > km ? k2 : km;
            km = k3 > km ? k3 : km;
            #pragma unroll
            for (int off = 32; off >= 1; off >>= 1) {
                const unsigned long long ks = __shfl_xor(km, off);
                if (ks > km) km = ks;
            }
            const unsigned int mono = (unsigned int)(km >> 10);
            mi[round] = 1023u - ((unsigned int)km & 1023u);
            const unsigned int bits = (mono & 0x80000000u) ? (mono & 0x7FFFFFFFu) : ~mono;
            const float vraw = __uint_as_float(bits);
            if (round == 0) vmax = vraw;
            const float e = __expf((vraw - vmax) * 0.125f);
            S += e;
            ev[round] = e;
            if (k0 == km) k0 = 0ull;
            if (k1 == km) k1 = 0ull;
            if (k2 == km) k2 = 0ull;
            if (k3 == km) k3 = 0ull;
        }

        // batched gathers: 8 independent L2 loads in flight
        float4 o = make_float4(0.f, 0.f, 0.f, 0.f);
        #pragma unroll
        for (int round = 0; round < 8; ++round) {
            const float4 vv = *(const float4*)&vtb[(size_t)mi[round] * C_ + lane * 4];
            o.x += ev[round] * vv.x; o.y += ev[round] * vv.y;
            o.z += ev[round] * vv.z; o.w += ev[round] * vv.w;
        }
        const float inv = 1.f / S;
        float* orow = (float*)&cand[r][0];   // union: out row over cand row r
        *(float4*)&orow[lane * 4] = make_float4(o.x*inv, o.y*inv, o.z*inv, o.w*inv);
    }
    __syncthreads();

    // ---- residual + (b, c, n) write ----
    const float sc = scale[0];
    const float* xb = x + (size_t)b * C_ * N_;
    float* ob = out + (size_t)b * C_ * N_;
    const int nl = t & 15;
    const int cg = t >> 4;               // 0..31
    const float* orow = (const float*)&cand[nl][0];
    #pragma unroll
    for (int i = 0; i < 8; ++i) {
        const int cc = i * 32 + cg;
        const size_t gi = (size_t)cc * N_ + n0 + nl;
        ob[gi] = xb[gi] + sc * orow[cc];
    }
}

extern "C" void kernel_launch(void* const* d_in, const int* in_sizes, int n_in,
                              void* d_out, int out_size, void* d_ws, size_t ws_size,
                              hipStream_t stream) {
    const float* x     = (const float*)d_in[0];
    const float* wq    = (const float*)d_in[1];
    const float* bq    = (const float*)d_in[2];
    const float* wk    = (const float*)d_in[3];
    const float* bk    = (const float*)d_in[4];
    const float* wv    = (const float*)d_in[5];
    const float* bv    = (const float*)d_in[6];
    const float* scale = (const float*)d_in[7];
    float* out = (float*)d_out;

    float* qk = (float*)d_ws;                    // (b,128,n) fp32 = 16.8 MB
    float* vt = qk + (size_t)B_ * 128 * N_;      // (b,n,c)  fp32 = 33.6 MB
    float* wt = vt + (size_t)B_ * N_ * C_;       // (c,384)  fp32 =  0.4 MB

    wt_kernel<<<dim3(256), 384, 0, stream>>>(wq, wk, wv, wt);
    proj_kernel<<<dim3(12, 4, B_), 256, 0, stream>>>(x, wt, bq, bk, bv, qk, vt);
    attn_kernel<<<dim3(N_ / 16, B_), 512, 0, stream>>>(x, qk, vt, scale, out);
}